// Round 1
// baseline (459.039 us; speedup 1.0000x reference)
//
#include <hip/hip_runtime.h>
#include <hip/hip_bf16.h>
#include <cstdint>
#include <cstddef>

// ---------------------------------------------------------------------------
// MaskedSelfAttention: B=2, T=2048, C=2048, NH=16, NG=4, D=128
// sliding window 512 + sink 4, RoPE base 10000, pos 0.
// fp32 I/O; bf16 MFMA internally (fp32 accum).
// Workspace (32 MB):
//   [0,16M):  xb [4096][2048] bf16 -> later At [2][2048][2048] bf16
//   [16,28M): Wqkvt [3072][2048] bf16 -> later Wot [2048][2048] (16-24M)
// d_out scratch (33.5 MB fp32, dead until final O-GEMM):
//   [0,16.78M): Qb [4096][2048] bf16
//   [16.78,20.97M): Kb [4096][512] bf16
//   [20.97,25.17M): Vt [512][4096] bf16
// ---------------------------------------------------------------------------

typedef short s16;
typedef short short8 __attribute__((ext_vector_type(8)));
typedef short s16x4  __attribute__((ext_vector_type(4)));
typedef float f32x4  __attribute__((ext_vector_type(4)));

#define MFMA16(a, b, c) __builtin_amdgcn_mfma_f32_16x16x32_bf16((a), (b), (c), 0, 0, 0)

__device__ __forceinline__ float bf2f(s16 u) {
    union { float f; uint32_t i; } v;
    v.i = ((uint32_t)(uint16_t)u) << 16;
    return v.f;
}
__device__ __forceinline__ s16 f2bf(float f) {
    union { float f; uint32_t i; } v;
    v.f = f;
    uint32_t r = v.i + 0x7FFFu + ((v.i >> 16) & 1u);   // RNE
    return (s16)(r >> 16);
}

// async global->LDS, 16 B per lane; LDS dest = wave-uniform base + lane*16
__device__ __forceinline__ void gload16(const s16* g, s16* l) {
    __builtin_amdgcn_global_load_lds(
        (const __attribute__((address_space(1))) void*)g,
        (__attribute__((address_space(3))) void*)l, 16, 0, 0);
}

// ---------------------------------------------------------------------------
// Elementwise fp32 -> bf16 cast (8 elems/thread).
// ---------------------------------------------------------------------------
__global__ __launch_bounds__(256)
void cast_bf16(const float* __restrict__ in, s16* __restrict__ out)
{
    size_t i = ((size_t)blockIdx.x * 256 + threadIdx.x) * 8;
    f32x4 f0 = *(const f32x4*)(in + i);
    f32x4 f1 = *(const f32x4*)(in + i + 4);
    short8 h;
    h[0]=f2bf(f0[0]); h[1]=f2bf(f0[1]); h[2]=f2bf(f0[2]); h[3]=f2bf(f0[3]);
    h[4]=f2bf(f1[0]); h[5]=f2bf(f1[1]); h[6]=f2bf(f1[2]); h[7]=f2bf(f1[3]);
    *(short8*)(out + i) = h;
}

// ---------------------------------------------------------------------------
// Transpose+cast all three QKV weights into Wqkvt [3072][2048]:
//   rows 0-2047 = Wq^T, 2048-2559 = Wk^T, 2560-3071 = Wv^T. K=2048 fixed.
// ---------------------------------------------------------------------------
__global__ __launch_bounds__(256)
void castT3(const float* __restrict__ Wq, const float* __restrict__ Wk,
            const float* __restrict__ Wv, s16* __restrict__ out)
{
    int z = blockIdx.z;
    const float* in; s16* dst; int N;
    if (z == 0)      { in = Wq; dst = out;                        N = 2048; }
    else if (z == 1) { in = Wk; dst = out + (size_t)2048 * 2048;  N = 512; }
    else             { in = Wv; dst = out + (size_t)2560 * 2048;  N = 512; }
    int n0 = blockIdx.x * 32, k0 = blockIdx.y * 32;
    if (n0 >= N) return;

    __shared__ float t[32][33];
    int tx = threadIdx.x & 31, ty = threadIdx.x >> 5;
    for (int i = 0; i < 32; i += 8)
        t[ty + i][tx] = in[(size_t)(k0 + ty + i) * N + n0 + tx];
    __syncthreads();
    for (int i = 0; i < 32; i += 8)
        dst[(size_t)(n0 + ty + i) * 2048 + k0 + tx] = f2bf(t[tx][ty + i]);
}

// ---------------------------------------------------------------------------
// Single-weight transpose+cast: fp32 [2048][2048] -> bf16 [2048][2048]^T.
// ---------------------------------------------------------------------------
__global__ __launch_bounds__(256)
void castT(const float* __restrict__ in, s16* __restrict__ out)
{
    __shared__ float t[32][33];
    int n0 = blockIdx.x * 32, k0 = blockIdx.y * 32;
    int tx = threadIdx.x & 31, ty = threadIdx.x >> 5;
    for (int i = 0; i < 32; i += 8)
        t[ty + i][tx] = in[(size_t)(k0 + ty + i) * 2048 + n0 + tx];
    __syncthreads();
    for (int i = 0; i < 32; i += 8)
        out[(size_t)(n0 + ty + i) * 2048 + k0 + tx] = f2bf(t[tx][ty + i]);
}

// ---------------------------------------------------------------------------
// GEMM: out = A[M][K] x Bt[N][K]^T + bias. m97 staging (global_load_lds w16),
// tile 128x128, BK=32, 4 waves, wave = 64x64 (4x4 MFMA frags).
// MODE 0: QKV split epilogue (n<2048 -> Qb bf16; n<2560 -> Kb bf16;
//         else Vt bf16 transposed).  MODE 2: fp32 out + bias.
// mfma_f32_16x16x32_bf16 layouts (verified m89/m91):
//   A-frag: A[m=lane&15][k=(lane>>4)*8+j]; B-frag: B[k=(lane>>4)*8+j][n=lane&15]
//   C/D:    row=(lane>>4)*4+reg, col=lane&15
// ---------------------------------------------------------------------------
template <int MODE>
__global__ __launch_bounds__(256)
void gemm_lds(const s16* __restrict__ A, const s16* __restrict__ Bt,
              const float* __restrict__ b0, const float* __restrict__ b1,
              const float* __restrict__ b2,
              void* __restrict__ o0, void* __restrict__ o1, void* __restrict__ o2,
              int M, int N, int K)
{
    __shared__ s16 As[128 * 32];
    __shared__ s16 Bs[128 * 32];

    const int tid  = threadIdx.x;
    const int m0   = blockIdx.x * 128, n0 = blockIdx.y * 128;
    const int lane = tid & 63, wv = tid >> 6;
    const int wm   = (wv >> 1) * 64, wn = (wv & 1) * 64;
    const int fr   = lane & 15, fq = lane >> 4;

    const int srow = wv * 16 + (lane >> 2);
    const int koff = (lane & 3) * 8;
    const s16* ga0 = A  + (size_t)(m0 + srow) * K + koff;
    const s16* ga1 = A  + (size_t)(m0 + 64 + srow) * K + koff;
    const s16* gb0 = Bt + (size_t)(n0 + srow) * K + koff;
    const s16* gb1 = Bt + (size_t)(n0 + 64 + srow) * K + koff;
    s16* la0 = &As[(wv * 16) * 32];
    s16* la1 = &As[(64 + wv * 16) * 32];
    s16* lb0 = &Bs[(wv * 16) * 32];
    s16* lb1 = &Bs[(64 + wv * 16) * 32];

    const s16* pa[4];
    const s16* pb[4];
    #pragma unroll
    for (int i = 0; i < 4; i++) {
        pa[i] = &As[(wm + i * 16 + fr) * 32 + fq * 8];
        pb[i] = &Bs[(wn + i * 16 + fr) * 32 + fq * 8];
    }

    f32x4 acc[4][4] = {};

    for (int k0 = 0; k0 < K; k0 += 32) {
        __syncthreads();
        gload16(ga0 + k0, la0);
        gload16(ga1 + k0, la1);
        gload16(gb0 + k0, lb0);
        gload16(gb1 + k0, lb1);
        __syncthreads();

        short8 af[4], bfr[4];
        #pragma unroll
        for (int i = 0; i < 4; i++) af[i] = *(const short8*)pa[i];
        #pragma unroll
        for (int i = 0; i < 4; i++) bfr[i] = *(const short8*)pb[i];

        #pragma unroll
        for (int mi = 0; mi < 4; mi++)
            #pragma unroll
            for (int ni = 0; ni < 4; ni++)
                acc[mi][ni] = MFMA16(af[mi], bfr[ni], acc[mi][ni]);
    }

    #pragma unroll
    for (int mi = 0; mi < 4; mi++)
        #pragma unroll
        for (int ni = 0; ni < 4; ni++)
            #pragma unroll
            for (int r = 0; r < 4; r++) {
                int m = m0 + wm + mi * 16 + fq * 4 + r;
                int n = n0 + wn + ni * 16 + fr;
                float v = acc[mi][ni][r];
                if (MODE == 0) {
                    if (n < 2048)
                        ((s16*)o0)[(size_t)m * 2048 + n] = f2bf(v + b0[n]);
                    else if (n < 2560)
                        ((s16*)o1)[(size_t)m * 512 + (n - 2048)] = f2bf(v + b1[n - 2048]);
                    else
                        ((s16*)o2)[(size_t)(n - 2560) * 4096 + m] = f2bf(v + b2[n - 2560]);
                } else {
                    ((float*)o0)[(size_t)m * N + n] = v + b0[n];
                }
            }
}

// ---------------------------------------------------------------------------
// Fused RoPE for Q (16 heads) and K (4 heads), in-place, pos 0.
// Blocks [0,16384) -> Qb rows; [16384,20480) -> Kb rows.
// ---------------------------------------------------------------------------
__global__ __launch_bounds__(256)
void rope2_kernel(s16* __restrict__ Qb, s16* __restrict__ Kb)
{
    int bx = blockIdx.x;
    s16* buf; int nheads; int idx;
    if (bx < 16384) { buf = Qb; nheads = 16; idx = bx * 256 + threadIdx.x; }
    else            { buf = Kb; nheads = 4;  idx = (bx - 16384) * 256 + threadIdx.x; }

    int i   = idx & 63;
    int hi  = idx >> 6;
    int h   = hi % nheads;
    int row = hi / nheads;
    int t   = row & 2047;

    float inv_freq = __powf(10000.0f, -(float)i * (1.0f / 64.0f));
    float ang = (float)t * inv_freq;
    float c = cosf(ang);
    float s = sinf(ang);

    size_t base = (size_t)row * ((size_t)nheads * 128) + (size_t)h * 128 + i;
    float x1 = bf2f(buf[base]);
    float x2 = bf2f(buf[base + 64]);
    buf[base]      = f2bf(x1 * c - x2 * s);
    buf[base + 64] = f2bf(x1 * s + x2 * c);
}

// ---------------------------------------------------------------------------
// Flash attention, sliding window + sink; both batches (z=b).
// v2: no K/V LDS staging, no barriers. K and V fragments are loaded straight
// from global (per-lane contiguous 16 B = exact MFMA frag pattern); the
// per-(b,g) K/V working set (1 MB) is L2/L3-resident and the 4 waves of a
// block share the CU's L1. Swapped QK^T (mfma(K,Q) -> S^T) puts each q-row's
// chunk scores in-lane: softmax reduce = 7 fmax + 2 shfl (was 16 shfl), m/l
// state is one scalar per lane. exp2-domain math; defer-max (THR=8) skips the
// O-rescale on most chunks. Only LDS left: wave-private Ps for P^T->A-frag.
// Q [4096][2048] bf16; Kb [4096][512]; Vt [512][4096]; At [2][2048][2048].
// Block 256 thr = 4 independent waves; 16 q rows/wave; key chunks of 32.
// ---------------------------------------------------------------------------
__global__ __launch_bounds__(256)
void attn_kernel(const s16* __restrict__ Q, const s16* __restrict__ Kb,
                 const s16* __restrict__ Vt, s16* __restrict__ At)
{
    __shared__ s16 Ps[4][16][40];   // [wave][q][key] P^T staging (wave-private)

    const int b = blockIdx.z;
    const int h = blockIdx.y, g = h >> 2;
    const int t0 = (31 - blockIdx.x) * 64;    // heavy blocks dispatch first
    const int tid = threadIdx.x, lane = tid & 63, wv = tid >> 6;
    const int fr = lane & 15, fq = lane >> 4;
    const int tw = t0 + wv * 16;
    s16* O = At + (size_t)b * 4194304;

    const float SCL2 = 0.12751743f;     // 128^-0.5 * log2(e)  (exp2 domain)
    const float NEG  = -1e9f;
    const float THR2 = 11.541560f;      // 8 * log2(e): defer-max threshold

    // Q as B-frag: B[k=fq*8+j][n=fr] = Q[tw+fr][d0+fq*8+j]
    short8 qf[4];
    {
        const s16* qrow = Q + (size_t)(b * 2048 + tw + fr) * 2048 + h * 128 + fq * 8;
        qf[0] = *(const short8*)(qrow);
        qf[1] = *(const short8*)(qrow + 32);
        qf[2] = *(const short8*)(qrow + 64);
        qf[3] = *(const short8*)(qrow + 96);
    }

    // per-lane global frag bases:
    // K A-frag value: Kb[(b*2048 + key + fr)*512 + g*128 + dc*32 + fq*8 + j]
    const s16* kb0 = Kb + (size_t)(b * 2048 + fr) * 512 + g * 128 + fq * 8;
    // V B-frag value: Vt[(g*128 + n0*16 + fr)*4096 + b*2048 + kbase + fq*8 + j]
    const s16* vb0 = Vt + (size_t)(g * 128 + fr) * 4096 + b * 2048 + fq * 8;

    f32x4 Oacc[8] = {};
    float m2 = NEG, l_s = 0.0f;         // softmax state for q = tw + fr (log2 dom.)
    const int tq = tw + fr;

    int lo = t0 - 512; if (lo < 0) lo = 0;
    const int c0   = lo >> 5;
    const int cend = (t0 + 63) >> 5;
    const int nch  = cend - c0 + 1 + (c0 > 0 ? 1 : 0);

    #define CHUNKBASE(ic) ((((c0) > 0) ? ((ic) == 0 ? 0 : c0 + (ic) - 1) : (ic)) * 32)

    for (int ic = 0; ic < nch; ic++) {
        const int kbase = CHUNKBASE(ic);

        // S^T = K Q^T : C row = key (kn*16 + fq*4 + r), col = q (fr)
        const s16* kp = kb0 + (size_t)kbase * 512;
        f32x4 sc[2] = {};
        #pragma unroll
        for (int kn = 0; kn < 2; kn++)
            #pragma unroll
            for (int dc = 0; dc < 4; dc++) {
                short8 kf = *(const short8*)(kp + kn * 16 * 512 + dc * 32);
                sc[kn] = MFMA16(kf, qf[dc], sc[kn]);
            }

        // mask + scale into log2 domain; all 8 values belong to q = tq
        float sv[8];
        #pragma unroll
        for (int kn = 0; kn < 2; kn++)
            #pragma unroll
            for (int r = 0; r < 4; r++) {
                int j = kbase + kn * 16 + fq * 4 + r;
                bool ok = (j <= tq) && ((j >= tq - 512) || (j < 4));
                sv[kn * 4 + r] = ok ? sc[kn][r] * SCL2 : NEG;
            }

        // chunk max for this q-row: in-lane over 8, then across the 4 fq lanes
        float cm = sv[0];
        #pragma unroll
        for (int i = 1; i < 8; i++) cm = fmaxf(cm, sv[i]);
        cm = fmaxf(cm, __shfl_xor(cm, 16));
        cm = fmaxf(cm, __shfl_xor(cm, 32));

        // defer-max: only rescale when some row grew by > THR2
        if (__any(cm > m2 + THR2)) {
            float nm    = fmaxf(m2, cm);
            float alpha = exp2f(m2 - nm);
            m2  = nm;
            l_s *= alpha;
            #pragma unroll
            for (int r = 0; r < 4; r++) {
                // Oacc row fq*4+r needs alpha of q-row (fq*4+r): fetch from a
                // lane whose fr == that row (state replicated across fq lanes)
                float ar = __shfl(alpha, (lane & 48) + fq * 4 + r);
                #pragma unroll
                for (int n0 = 0; n0 < 8; n0++) Oacc[n0][r] *= ar;
            }
        }

        float p[8], ps = 0.0f;
        #pragma unroll
        for (int i = 0; i < 8; i++) { p[i] = exp2f(sv[i] - m2); ps += p[i]; }
        ps += __shfl_xor(ps, 16);
        ps += __shfl_xor(ps, 32);
        l_s += ps;

        // P^T (C layout [key][q]) -> Ps[q][key] so pf reads an A-frag
        s16x4 w0, w1;
        #pragma unroll
        for (int r = 0; r < 4; r++) { w0[r] = f2bf(p[r]); w1[r] = f2bf(p[4 + r]); }
        *(s16x4*)&Ps[wv][fr][fq * 4]      = w0;   // keys kn=0: fq*4..fq*4+3
        *(s16x4*)&Ps[wv][fr][16 + fq * 4] = w1;   // keys kn=1
        __threadfence_block();
        short8 pf = *(const short8*)&Ps[wv][fr][fq * 8];  // A[m=q][k=key]

        // PV: B-frag of V straight from global
        const s16* vp = vb0 + kbase;
        #pragma unroll
        for (int n0 = 0; n0 < 8; n0++) {
            short8 vf = *(const short8*)(vp + (size_t)n0 * 16 * 4096);
            Oacc[n0] = MFMA16(pf, vf, Oacc[n0]);
        }
    }

    // epilogue: l for Oacc row fq*4+r lives at lane with fr == fq*4+r
    float linv[4];
    #pragma unroll
    for (int r = 0; r < 4; r++)
        linv[r] = 1.0f / __shfl(l_s, (lane & 48) + fq * 4 + r);
    #pragma unroll
    for (int n0 = 0; n0 < 8; n0++)
        #pragma unroll
        for (int r = 0; r < 4; r++) {
            int t = tw + fq * 4 + r;
            O[(size_t)t * 2048 + h * 128 + n0 * 16 + fr] =
                f2bf(Oacc[n0][r] * linv[r]);
        }
}

// ---------------------------------------------------------------------------
// Launcher (memory map at top of file).
// ---------------------------------------------------------------------------
extern "C" void kernel_launch(void* const* d_in, const int* in_sizes, int n_in,
                              void* d_out, int out_size, void* d_ws, size_t ws_size,
                              hipStream_t stream)
{
    const float* x  = (const float*)d_in[0];
    const float* Wq = (const float*)d_in[1];
    const float* bq = (const float*)d_in[2];
    const float* Wk = (const float*)d_in[3];
    const float* bk = (const float*)d_in[4];
    const float* Wv = (const float*)d_in[5];
    const float* bv = (const float*)d_in[6];
    const float* Wo = (const float*)d_in[7];
    const float* bo = (const float*)d_in[8];
    float* out = (float*)d_out;

    if (ws_size < 33554432) return;

    char* ws = (char*)d_ws;
    s16* xb    = (s16*)(ws + 0);           // [4096][2048] bf16 (16 MB)
    s16* At    = (s16*)(ws + 0);           // [2][2048][2048] bf16 (after xb dies)
    s16* Wqkvt = (s16*)(ws + 16777216);    // [3072][2048] bf16 (12 MB)
    s16* Wot   = (s16*)(ws + 16777216);    // [2048][2048] bf16 (after QKV GEMM)
    s16* Qb    = (s16*)d_out;                              // [4096][2048] bf16
    s16* Kb    = (s16*)((char*)d_out + 16777216);          // [4096][512]  bf16
    s16* Vt    = (s16*)((char*)d_out + 20971520);          // [512][4096]  bf16

    // x -> bf16
    cast_bf16<<<4096, 256, 0, stream>>>(x, xb);

    // QKV weights -> Wqkvt (transposed bf16)
    castT3<<<dim3(64, 64, 3), 256, 0, stream>>>(Wq, Wk, Wv, Wqkvt);

    // fused QKV projection with split epilogue
    gemm_lds<0><<<dim3(32, 24), 256, 0, stream>>>(xb, Wqkvt, bq, bk, bv,
                                                  Qb, Kb, Vt, 4096, 3072, 2048);

    // RoPE on Q and K (one launch)
    rope2_kernel<<<20480, 256, 0, stream>>>(Qb, Kb);

    // O weight (overwrites Wqkvt; stream-ordered after QKV GEMM)
    castT<<<dim3(64, 64), 256, 0, stream>>>(Wo, Wot);

    // attention, both batches (xb dead -> At reuses its space)
    attn_kernel<<<dim3(32, 16, 2), 256, 0, stream>>>(Qb, Kb, Vt, At);

    // output projection: At [4096][2048] x Wot + bo -> out fp32
    gemm_lds<2><<<dim3(32, 16), 256, 0, stream>>>(At, Wot, bo, nullptr, nullptr,
                                                  out, nullptr, nullptr,
                                                  4096, 2048, 2048);
}

// Round 2
// 347.126 us; speedup vs baseline: 1.3224x; 1.3224x over previous
//
#include <hip/hip_runtime.h>
#include <hip/hip_bf16.h>
#include <cstdint>
#include <cstddef>

// ---------------------------------------------------------------------------
// MaskedSelfAttention: B=2, T=2048, C=2048, NH=16, NG=4, D=128
// sliding window 512 + sink 4, RoPE base 10000, pos 0.
// fp32 I/O; bf16 MFMA internally (fp32 accum).
// Workspace (32 MB):
//   [0,16M):  xb [4096][2048] bf16 -> later At [2][2048][2048] bf16
//   [16,28M): Wqkvt [3072][2048] bf16 -> later Wot [2048][2048] (16-24M)
// d_out scratch (33.5 MB fp32, dead until final O-GEMM):
//   [0,16.78M): Qb [4096][2048] bf16
//   [16.78,20.97M): Kb [4096][512] bf16
//   [20.97,25.17M): Vt [512][4096] bf16
// ---------------------------------------------------------------------------

typedef short s16;
typedef short short8 __attribute__((ext_vector_type(8)));
typedef short s16x4  __attribute__((ext_vector_type(4)));
typedef float f32x4  __attribute__((ext_vector_type(4)));

#define MFMA16(a, b, c) __builtin_amdgcn_mfma_f32_16x16x32_bf16((a), (b), (c), 0, 0, 0)

__device__ __forceinline__ float bf2f(s16 u) {
    union { float f; uint32_t i; } v;
    v.i = ((uint32_t)(uint16_t)u) << 16;
    return v.f;
}
__device__ __forceinline__ s16 f2bf(float f) {
    union { float f; uint32_t i; } v;
    v.f = f;
    uint32_t r = v.i + 0x7FFFu + ((v.i >> 16) & 1u);   // RNE
    return (s16)(r >> 16);
}

// async global->LDS, 16 B per lane; LDS dest = wave-uniform base + lane*16
__device__ __forceinline__ void gload16(const s16* g, s16* l) {
    __builtin_amdgcn_global_load_lds(
        (const __attribute__((address_space(1))) void*)g,
        (__attribute__((address_space(3))) void*)l, 16, 0, 0);
}

// ---------------------------------------------------------------------------
// Elementwise fp32 -> bf16 cast (8 elems/thread).
// ---------------------------------------------------------------------------
__global__ __launch_bounds__(256)
void cast_bf16(const float* __restrict__ in, s16* __restrict__ out)
{
    size_t i = ((size_t)blockIdx.x * 256 + threadIdx.x) * 8;
    f32x4 f0 = *(const f32x4*)(in + i);
    f32x4 f1 = *(const f32x4*)(in + i + 4);
    short8 h;
    h[0]=f2bf(f0[0]); h[1]=f2bf(f0[1]); h[2]=f2bf(f0[2]); h[3]=f2bf(f0[3]);
    h[4]=f2bf(f1[0]); h[5]=f2bf(f1[1]); h[6]=f2bf(f1[2]); h[7]=f2bf(f1[3]);
    *(short8*)(out + i) = h;
}

// ---------------------------------------------------------------------------
// Transpose+cast all three QKV weights into Wqkvt [3072][2048]:
//   rows 0-2047 = Wq^T, 2048-2559 = Wk^T, 2560-3071 = Wv^T. K=2048 fixed.
// ---------------------------------------------------------------------------
__global__ __launch_bounds__(256)
void castT3(const float* __restrict__ Wq, const float* __restrict__ Wk,
            const float* __restrict__ Wv, s16* __restrict__ out)
{
    int z = blockIdx.z;
    const float* in; s16* dst; int N;
    if (z == 0)      { in = Wq; dst = out;                        N = 2048; }
    else if (z == 1) { in = Wk; dst = out + (size_t)2048 * 2048;  N = 512; }
    else             { in = Wv; dst = out + (size_t)2560 * 2048;  N = 512; }
    int n0 = blockIdx.x * 32, k0 = blockIdx.y * 32;
    if (n0 >= N) return;

    __shared__ float t[32][33];
    int tx = threadIdx.x & 31, ty = threadIdx.x >> 5;
    for (int i = 0; i < 32; i += 8)
        t[ty + i][tx] = in[(size_t)(k0 + ty + i) * N + n0 + tx];
    __syncthreads();
    for (int i = 0; i < 32; i += 8)
        dst[(size_t)(n0 + ty + i) * 2048 + k0 + tx] = f2bf(t[tx][ty + i]);
}

// ---------------------------------------------------------------------------
// Single-weight transpose+cast: fp32 [2048][2048] -> bf16 [2048][2048]^T.
// ---------------------------------------------------------------------------
__global__ __launch_bounds__(256)
void castT(const float* __restrict__ in, s16* __restrict__ out)
{
    __shared__ float t[32][33];
    int n0 = blockIdx.x * 32, k0 = blockIdx.y * 32;
    int tx = threadIdx.x & 31, ty = threadIdx.x >> 5;
    for (int i = 0; i < 32; i += 8)
        t[ty + i][tx] = in[(size_t)(k0 + ty + i) * 2048 + n0 + tx];
    __syncthreads();
    for (int i = 0; i < 32; i += 8)
        out[(size_t)(n0 + ty + i) * 2048 + k0 + tx] = f2bf(t[tx][ty + i]);
}

// ---------------------------------------------------------------------------
// GEMM: out = A[M][K] x Bt[N][K]^T + bias. m97 staging (global_load_lds w16),
// tile 128x128, BK=32, 4 waves, wave = 64x64 (4x4 MFMA frags).
// MODE 0: QKV split epilogue (n<2048 -> Qb bf16; n<2560 -> Kb bf16;
//         else Vt bf16 transposed).  MODE 2: fp32 out + bias.
// mfma_f32_16x16x32_bf16 layouts (verified m89/m91):
//   A-frag: A[m=lane&15][k=(lane>>4)*8+j]; B-frag: B[k=(lane>>4)*8+j][n=lane&15]
//   C/D:    row=(lane>>4)*4+reg, col=lane&15
// ---------------------------------------------------------------------------
template <int MODE>
__global__ __launch_bounds__(256)
void gemm_lds(const s16* __restrict__ A, const s16* __restrict__ Bt,
              const float* __restrict__ b0, const float* __restrict__ b1,
              const float* __restrict__ b2,
              void* __restrict__ o0, void* __restrict__ o1, void* __restrict__ o2,
              int M, int N, int K)
{
    __shared__ s16 As[128 * 32];
    __shared__ s16 Bs[128 * 32];

    const int tid  = threadIdx.x;
    const int m0   = blockIdx.x * 128, n0 = blockIdx.y * 128;
    const int lane = tid & 63, wv = tid >> 6;
    const int wm   = (wv >> 1) * 64, wn = (wv & 1) * 64;
    const int fr   = lane & 15, fq = lane >> 4;

    const int srow = wv * 16 + (lane >> 2);
    const int koff = (lane & 3) * 8;
    const s16* ga0 = A  + (size_t)(m0 + srow) * K + koff;
    const s16* ga1 = A  + (size_t)(m0 + 64 + srow) * K + koff;
    const s16* gb0 = Bt + (size_t)(n0 + srow) * K + koff;
    const s16* gb1 = Bt + (size_t)(n0 + 64 + srow) * K + koff;
    s16* la0 = &As[(wv * 16) * 32];
    s16* la1 = &As[(64 + wv * 16) * 32];
    s16* lb0 = &Bs[(wv * 16) * 32];
    s16* lb1 = &Bs[(64 + wv * 16) * 32];

    const s16* pa[4];
    const s16* pb[4];
    #pragma unroll
    for (int i = 0; i < 4; i++) {
        pa[i] = &As[(wm + i * 16 + fr) * 32 + fq * 8];
        pb[i] = &Bs[(wn + i * 16 + fr) * 32 + fq * 8];
    }

    f32x4 acc[4][4] = {};

    for (int k0 = 0; k0 < K; k0 += 32) {
        __syncthreads();
        gload16(ga0 + k0, la0);
        gload16(ga1 + k0, la1);
        gload16(gb0 + k0, lb0);
        gload16(gb1 + k0, lb1);
        __syncthreads();

        short8 af[4], bfr[4];
        #pragma unroll
        for (int i = 0; i < 4; i++) af[i] = *(const short8*)pa[i];
        #pragma unroll
        for (int i = 0; i < 4; i++) bfr[i] = *(const short8*)pb[i];

        #pragma unroll
        for (int mi = 0; mi < 4; mi++)
            #pragma unroll
            for (int ni = 0; ni < 4; ni++)
                acc[mi][ni] = MFMA16(af[mi], bfr[ni], acc[mi][ni]);
    }

    #pragma unroll
    for (int mi = 0; mi < 4; mi++)
        #pragma unroll
        for (int ni = 0; ni < 4; ni++)
            #pragma unroll
            for (int r = 0; r < 4; r++) {
                int m = m0 + wm + mi * 16 + fq * 4 + r;
                int n = n0 + wn + ni * 16 + fr;
                float v = acc[mi][ni][r];
                if (MODE == 0) {
                    if (n < 2048)
                        ((s16*)o0)[(size_t)m * 2048 + n] = f2bf(v + b0[n]);
                    else if (n < 2560)
                        ((s16*)o1)[(size_t)m * 512 + (n - 2048)] = f2bf(v + b1[n - 2048]);
                    else
                        ((s16*)o2)[(size_t)(n - 2560) * 4096 + m] = f2bf(v + b2[n - 2560]);
                } else {
                    ((float*)o0)[(size_t)m * N + n] = v + b0[n];
                }
            }
}

// ---------------------------------------------------------------------------
// Fused RoPE for Q (16 heads) and K (4 heads), in-place, pos 0.
// Blocks [0,16384) -> Qb rows; [16384,20480) -> Kb rows.
// ---------------------------------------------------------------------------
__global__ __launch_bounds__(256)
void rope2_kernel(s16* __restrict__ Qb, s16* __restrict__ Kb)
{
    int bx = blockIdx.x;
    s16* buf; int nheads; int idx;
    if (bx < 16384) { buf = Qb; nheads = 16; idx = bx * 256 + threadIdx.x; }
    else            { buf = Kb; nheads = 4;  idx = (bx - 16384) * 256 + threadIdx.x; }

    int i   = idx & 63;
    int hi  = idx >> 6;
    int h   = hi % nheads;
    int row = hi / nheads;
    int t   = row & 2047;

    float inv_freq = __powf(10000.0f, -(float)i * (1.0f / 64.0f));
    float ang = (float)t * inv_freq;
    float c = cosf(ang);
    float s = sinf(ang);

    size_t base = (size_t)row * ((size_t)nheads * 128) + (size_t)h * 128 + i;
    float x1 = bf2f(buf[base]);
    float x2 = bf2f(buf[base + 64]);
    buf[base]      = f2bf(x1 * c - x2 * s);
    buf[base + 64] = f2bf(x1 * s + x2 * c);
}

// ---------------------------------------------------------------------------
// Flash attention v3 (hybrid), sliding window + sink; both batches (z=b).
// Staging/pipeline = v1 (proven latency-hider): double-buffered K/V in LDS,
// register prefetch, 1 barrier per 32-key chunk, heavy-first dispatch.
// Softmax = v2 (proven correct, 4x less VALU): swapped QK^T (mfma(K,Q)->S^T)
// puts a q-row's 8 chunk scores in-lane; reduce = 7 fmax + 2 shfl; m/l state
// one scalar/lane (log2 domain); defer-max (THR=8) skips most O-rescales;
// P^T->A-frag staged via wave-private Ps (2x ds_write_b64, was 8x b16).
// setprio(1) wrapped around both MFMA clusters (T5, attn-proven).
// Q [4096][2048] bf16; Kb [4096][512]; Vt [512][4096]; At [2][2048][2048].
// ---------------------------------------------------------------------------
__global__ __launch_bounds__(256)
void attn_kernel(const s16* __restrict__ Q, const s16* __restrict__ Kb,
                 const s16* __restrict__ Vt, s16* __restrict__ At)
{
    __shared__ s16 Ks[2][32][136];   // [buf][key][d]
    __shared__ s16 Vs[2][128][40];   // [buf][d][key]
    __shared__ s16 Ps[4][16][40];    // [wave][q][key] P^T staging (wave-private)

    const int b = blockIdx.z;
    const int h = blockIdx.y, g = h >> 2;
    const int t0 = (31 - blockIdx.x) * 64;    // heavy blocks dispatch first
    const int tid = threadIdx.x, lane = tid & 63, wv = tid >> 6;
    const int fr = lane & 15, fq = lane >> 4;
    const int tw = t0 + wv * 16;
    s16* O = At + (size_t)b * 4194304;

    const float SCL2 = 0.12751743f;     // 128^-0.5 * log2(e)  (exp2 domain)
    const float NEG  = -1e9f;
    const float THR2 = 11.541560f;      // 8 * log2(e): defer-max threshold

    // per-thread staging geometry (2 chunks of work for K and V each)
    int kr[2], kc[2], vd[2], vc[2];
    const s16 *gK[2], *gV[2];
    #pragma unroll
    for (int it = 0; it < 2; it++) {
        int idx = it * 2048 + tid * 8;
        kr[it] = idx >> 7;  kc[it] = idx & 127;
        vd[it] = idx >> 5;  vc[it] = idx & 31;
        gK[it] = Kb + (size_t)(b * 2048 + kr[it]) * 512 + g * 128 + kc[it];
        gV[it] = Vt + (size_t)(g * 128 + vd[it]) * 4096 + b * 2048 + vc[it];
    }

    // Q as B-frag: B[k=fq*8+j][n=fr] = Q[tw+fr][d0+fq*8+j]  (whole kernel)
    short8 qf[4];
    {
        const s16* qrow = Q + (size_t)(b * 2048 + tw + fr) * 2048 + h * 128 + fq * 8;
        qf[0] = *(const short8*)(qrow);
        qf[1] = *(const short8*)(qrow + 32);
        qf[2] = *(const short8*)(qrow + 64);
        qf[3] = *(const short8*)(qrow + 96);
    }

    f32x4 Oacc[8] = {};
    float m2 = NEG, l_s = 0.0f;         // softmax state for q = tw + fr
    const int tq = tw + fr;

    int lo = t0 - 512; if (lo < 0) lo = 0;
    const int c0   = lo >> 5;
    const int cend = (t0 + 63) >> 5;
    const int nch  = cend - c0 + 1 + (c0 > 0 ? 1 : 0);

    #define CHUNKBASE(ic) ((((c0) > 0) ? ((ic) == 0 ? 0 : c0 + (ic) - 1) : (ic)) * 32)

    short8 kpre[2], vpre[2];
    {   // prefetch + store chunk 0 into buf 0
        int kb = CHUNKBASE(0);
        #pragma unroll
        for (int it = 0; it < 2; it++) {
            kpre[it] = *(const short8*)(gK[it] + (size_t)kb * 512);
            vpre[it] = *(const short8*)(gV[it] + kb);
        }
        #pragma unroll
        for (int it = 0; it < 2; it++) {
            *(short8*)&Ks[0][kr[it]][kc[it]] = kpre[it];
            *(short8*)&Vs[0][vd[it]][vc[it]] = vpre[it];
        }
    }
    __syncthreads();

    for (int ic = 0; ic < nch; ic++) {
        const int cur = ic & 1;
        const int kbase = CHUNKBASE(ic);
        const bool pre = (ic + 1 < nch);
        if (pre) {
            int kb = CHUNKBASE(ic + 1);
            #pragma unroll
            for (int it = 0; it < 2; it++) {
                kpre[it] = *(const short8*)(gK[it] + (size_t)kb * 512);
                vpre[it] = *(const short8*)(gV[it] + kb);
            }
        }

        // S^T = K Q^T : C row = key (kn*16 + fq*4 + r), col = q (fr).
        // K A-frag read from LDS is the SAME pattern as v1's kf read.
        f32x4 sc[2] = {{0.f,0.f,0.f,0.f},{0.f,0.f,0.f,0.f}};
        __builtin_amdgcn_s_setprio(1);
        #pragma unroll
        for (int kn = 0; kn < 2; kn++)
            #pragma unroll
            for (int dc = 0; dc < 4; dc++) {
                short8 kf = *(const short8*)&Ks[cur][kn * 16 + fr][dc * 32 + fq * 8];
                sc[kn] = MFMA16(kf, qf[dc], sc[kn]);
            }
        __builtin_amdgcn_s_setprio(0);

        // mask + scale into log2 domain; all 8 values belong to q = tq
        float sv[8];
        #pragma unroll
        for (int kn = 0; kn < 2; kn++)
            #pragma unroll
            for (int r = 0; r < 4; r++) {
                int j = kbase + kn * 16 + fq * 4 + r;
                bool ok = (j <= tq) && ((j >= tq - 512) || (j < 4));
                sv[kn * 4 + r] = ok ? sc[kn][r] * SCL2 : NEG;
            }

        // chunk max for this q-row: in-lane over 8, then across the 4 fq groups
        float cm = fmaxf(sv[0], sv[1]);
        #pragma unroll
        for (int i = 2; i < 8; i++) cm = fmaxf(cm, sv[i]);
        cm = fmaxf(cm, __shfl_xor(cm, 16));
        cm = fmaxf(cm, __shfl_xor(cm, 32));

        // defer-max: only rescale when some row grew by > THR2
        if (__any(cm > m2 + THR2)) {
            float nm    = fmaxf(m2, cm);
            float alpha = exp2f(m2 - nm);
            m2  = nm;
            l_s *= alpha;
            #pragma unroll
            for (int r = 0; r < 4; r++) {
                // Oacc row fq*4+r needs alpha of q-row fq*4+r (state is
                // replicated across fq groups; pull from lane fq*16 + fq*4+r)
                float ar = __shfl(alpha, (lane & 48) + fq * 4 + r);
                #pragma unroll
                for (int n0 = 0; n0 < 8; n0++) Oacc[n0][r] *= ar;
            }
        }

        float p[8], ps = 0.0f;
        #pragma unroll
        for (int i = 0; i < 8; i++) { p[i] = exp2f(sv[i] - m2); ps += p[i]; }
        ps += __shfl_xor(ps, 16);
        ps += __shfl_xor(ps, 32);
        l_s += ps;

        // P^T (C layout [key][q]) -> Ps[q][key] so pf reads an A-frag
        s16x4 w0, w1;
        #pragma unroll
        for (int r = 0; r < 4; r++) { w0[r] = f2bf(p[r]); w1[r] = f2bf(p[4 + r]); }
        *(s16x4*)&Ps[wv][fr][fq * 4]      = w0;   // keys kn=0: fq*4..fq*4+3
        *(s16x4*)&Ps[wv][fr][16 + fq * 4] = w1;   // keys kn=1
        __threadfence_block();
        short8 pf = *(const short8*)&Ps[wv][fr][fq * 8];  // A[m=q][k=key]

        __builtin_amdgcn_s_setprio(1);
        #pragma unroll
        for (int n0 = 0; n0 < 8; n0++) {
            short8 vf = *(const short8*)&Vs[cur][n0 * 16 + fr][fq * 8];
            Oacc[n0] = MFMA16(pf, vf, Oacc[n0]);
        }
        __builtin_amdgcn_s_setprio(0);

        if (pre) {
            #pragma unroll
            for (int it = 0; it < 2; it++) {
                *(short8*)&Ks[cur ^ 1][kr[it]][kc[it]] = kpre[it];
                *(short8*)&Vs[cur ^ 1][vd[it]][vc[it]] = vpre[it];
            }
            __syncthreads();
        }
    }

    // epilogue: l for Oacc row fq*4+r lives at lane fq*16 + (fq*4+r)
    float linv[4];
    #pragma unroll
    for (int r = 0; r < 4; r++)
        linv[r] = 1.0f / __shfl(l_s, (lane & 48) + fq * 4 + r);
    #pragma unroll
    for (int n0 = 0; n0 < 8; n0++)
        #pragma unroll
        for (int r = 0; r < 4; r++) {
            int t = tw + fq * 4 + r;
            O[(size_t)t * 2048 + h * 128 + n0 * 16 + fr] =
                f2bf(Oacc[n0][r] * linv[r]);
        }
}

// ---------------------------------------------------------------------------
// Launcher (memory map at top of file).
// ---------------------------------------------------------------------------
extern "C" void kernel_launch(void* const* d_in, const int* in_sizes, int n_in,
                              void* d_out, int out_size, void* d_ws, size_t ws_size,
                              hipStream_t stream)
{
    const float* x  = (const float*)d_in[0];
    const float* Wq = (const float*)d_in[1];
    const float* bq = (const float*)d_in[2];
    const float* Wk = (const float*)d_in[3];
    const float* bk = (const float*)d_in[4];
    const float* Wv = (const float*)d_in[5];
    const float* bv = (const float*)d_in[6];
    const float* Wo = (const float*)d_in[7];
    const float* bo = (const float*)d_in[8];
    float* out = (float*)d_out;

    if (ws_size < 33554432) return;

    char* ws = (char*)d_ws;
    s16* xb    = (s16*)(ws + 0);           // [4096][2048] bf16 (16 MB)
    s16* At    = (s16*)(ws + 0);           // [2][2048][2048] bf16 (after xb dies)
    s16* Wqkvt = (s16*)(ws + 16777216);    // [3072][2048] bf16 (12 MB)
    s16* Wot   = (s16*)(ws + 16777216);    // [2048][2048] bf16 (after QKV GEMM)
    s16* Qb    = (s16*)d_out;                              // [4096][2048] bf16
    s16* Kb    = (s16*)((char*)d_out + 16777216);          // [4096][512]  bf16
    s16* Vt    = (s16*)((char*)d_out + 20971520);          // [512][4096]  bf16

    // x -> bf16
    cast_bf16<<<4096, 256, 0, stream>>>(x, xb);

    // QKV weights -> Wqkvt (transposed bf16)
    castT3<<<dim3(64, 64, 3), 256, 0, stream>>>(Wq, Wk, Wv, Wqkvt);

    // fused QKV projection with split epilogue
    gemm_lds<0><<<dim3(32, 24), 256, 0, stream>>>(xb, Wqkvt, bq, bk, bv,
                                                  Qb, Kb, Vt, 4096, 3072, 2048);

    // RoPE on Q and K (one launch)
    rope2_kernel<<<20480, 256, 0, stream>>>(Qb, Kb);

    // O weight (overwrites Wqkvt; stream-ordered after QKV GEMM)
    castT<<<dim3(64, 64), 256, 0, stream>>>(Wo, Wot);

    // attention, both batches (xb dead -> At reuses its space)
    attn_kernel<<<dim3(32, 16, 2), 256, 0, stream>>>(Qb, Kb, Vt, At);

    // output projection: At [4096][2048] x Wot + bo -> out fp32
    gemm_lds<2><<<dim3(32, 16), 256, 0, stream>>>(At, Wot, bo, nullptr, nullptr,
                                                  out, nullptr, nullptr,
                                                  4096, 2048, 2048);
}